// Round 1
// baseline (150.505 us; speedup 1.0000x reference)
//
#include <hip/hip_runtime.h>
#include <stdint.h>

#define NN 4096
#define MM 8192
#define DD 512
// GEMM geometry: 256x256 tile, BK=32, 16 K-tiles, 4-buffer LDS ring.
#define NKT 16

typedef __bf16 bf16x8 __attribute__((ext_vector_type(8)));
typedef __bf16 bf16x4 __attribute__((ext_vector_type(4)));
typedef float f32x4 __attribute__((ext_vector_type(4)));
typedef float f32x16 __attribute__((ext_vector_type(16)));

__device__ __forceinline__ void load_lds16(const void* g, void* l) {
  // async global -> LDS, 16B/lane; LDS dest must be wave-uniform base + lane*16.
  __builtin_amdgcn_global_load_lds(
      (const __attribute__((address_space(1))) unsigned int*)g,
      (__attribute__((address_space(3))) unsigned int*)l, 16, 0, 0);
}

// VALU-pipe partial reduction (R7/R8-verified correct): x += rot16(x, k).
template <int CTRL>
__device__ __forceinline__ float dpp_radd(float x) {
  int xi = __float_as_int(x);
  int mv = __builtin_amdgcn_update_dpp(xi, xi, CTRL, 0xF, 0xF, false);
  return x + __int_as_float(mv);
}
__device__ __forceinline__ float swz_add_xor16(float x) {
  int sv = __builtin_amdgcn_ds_swizzle(__float_as_int(x), 0x401F);
  return x + __int_as_float(sv);
}

// 4 rows per 256-thread block, one wave per row. Fully-coalesced f32x4 loads,
// bf16x4 stores, exact fp32 row-norm, and out[]=IC init folded in. (Unchanged,
// verified; ~BW-bound.)
__global__ __launch_bounds__(256) void convert_norm_kernel(
    const float* __restrict__ X, const float* __restrict__ SV,
    __bf16* __restrict__ Xb, __bf16* __restrict__ SVb,
    float* __restrict__ x2, float* __restrict__ sv2,
    float* __restrict__ out, const float* __restrict__ IC) {
  int wid = blockIdx.x * 4 + (threadIdx.x >> 6);
  int lane = threadIdx.x & 63;
  const float* src;
  __bf16* dst;
  float* nrm;
  if (wid < NN) {
    src = X + (size_t)wid * DD;
    dst = Xb + (size_t)wid * DD;
    nrm = x2 + wid;
    if (lane == 0) out[wid] = IC[0];
  } else {
    int r = wid - NN;
    src = SV + (size_t)r * DD;
    dst = SVb + (size_t)r * DD;
    nrm = sv2 + r;
  }
  const f32x4* s = (const f32x4*)src;
  f32x4 a = s[lane];       // elements 4l..4l+3
  f32x4 b = s[lane + 64];  // elements 256+4l..
  float sum = a.x * a.x + a.y * a.y + a.z * a.z + a.w * a.w +
              b.x * b.x + b.y * b.y + b.z * b.z + b.w * b.w;
  bf16x4 ca = {(__bf16)a.x, (__bf16)a.y, (__bf16)a.z, (__bf16)a.w};
  bf16x4 cb = {(__bf16)b.x, (__bf16)b.y, (__bf16)b.z, (__bf16)b.w};
  *(bf16x4*)(dst + 4 * lane) = ca;
  *(bf16x4*)(dst + 256 + 4 * lane) = cb;
#pragma unroll
  for (int m = 32; m >= 1; m >>= 1) sum += __shfl_xor(sum, m, 64);
  if (lane == 0) *nrm = sum;
}

// ---- pipelined 256x256 GEMM ----
// 8 waves as 2(n) x 4(m); per wave 128n x 64m = 4x2 of mfma_32x32x16 -> 6
// ds_read_b128 per 8 MFMA (vs 1:1 before). BK=32, 4-buffer LDS ring (128 KiB),
// staged 3 K-tiles ahead with global_load_lds; ONE raw s_barrier + counted
// s_waitcnt vmcnt(8) per K-tile (never vmcnt(0) in steady state), so prefetch
// stays in flight across barriers (T3+T4). Conflict-free BK=32 swizzle:
// LDS slot (row, gs) holds global k-granule gs ^ ((row>>1)&3), applied on the
// global source address (global_load_lds writes linearly); banks verified:
// rows r..r+7 at fixed logical granule hit all 32 banks.
//
// Ring-safety invariants (1 barrier per tile): body t stages tile t+3 into
// buf[(t+3)&3] = buf[(t-1)&3], whose reads finished before the barrier ending
// tile t-1; vmcnt(8) before the barrier ending tile t leaves only tiles
// t+2,t+3 (8 loads/wave) in flight => tile t+1 landed for every wave.
__device__ __forceinline__ void stage_tile(const bf16x8* __restrict__ srcA,
                                           const bf16x8* __restrict__ srcB,
                                           bf16x8* AsD, bf16x8* BsD, int tid,
                                           int tt) {
  const bf16x8* sa = srcA + tt * 4;  // +tile k-offset (4 granules of 16B)
  const bf16x8* sb = srcB + tt * 4;
  load_lds16(sa, AsD + tid);                 // rows 0..127
  load_lds16(sa + 8192, AsD + 512 + tid);    // rows 128..255 (+128*64 granules)
  load_lds16(sb, BsD + tid);
  load_lds16(sb + 8192, BsD + 512 + tid);
}

__device__ __forceinline__ void compute_tile(f32x16 (&acc)[4][2],
                                             const bf16x8* AsB,
                                             const bf16x8* BsB, int aoff,
                                             int boff, int lhi, int rsw) {
#pragma unroll
  for (int ks = 0; ks < 2; ++ks) {
    const int gs = (2 * ks + lhi) ^ rsw;
    bf16x8 a0 = AsB[aoff + gs];
    bf16x8 a1 = AsB[aoff + 128 + gs];
    bf16x8 a2 = AsB[aoff + 256 + gs];
    bf16x8 a3 = AsB[aoff + 384 + gs];
    bf16x8 b0 = BsB[boff + gs];
    bf16x8 b1 = BsB[boff + 128 + gs];
    __builtin_amdgcn_s_setprio(1);
    acc[0][0] = __builtin_amdgcn_mfma_f32_32x32x16_bf16(a0, b0, acc[0][0], 0, 0, 0);
    acc[0][1] = __builtin_amdgcn_mfma_f32_32x32x16_bf16(a0, b1, acc[0][1], 0, 0, 0);
    acc[1][0] = __builtin_amdgcn_mfma_f32_32x32x16_bf16(a1, b0, acc[1][0], 0, 0, 0);
    acc[1][1] = __builtin_amdgcn_mfma_f32_32x32x16_bf16(a1, b1, acc[1][1], 0, 0, 0);
    acc[2][0] = __builtin_amdgcn_mfma_f32_32x32x16_bf16(a2, b0, acc[2][0], 0, 0, 0);
    acc[2][1] = __builtin_amdgcn_mfma_f32_32x32x16_bf16(a2, b1, acc[2][1], 0, 0, 0);
    acc[3][0] = __builtin_amdgcn_mfma_f32_32x32x16_bf16(a3, b0, acc[3][0], 0, 0, 0);
    acc[3][1] = __builtin_amdgcn_mfma_f32_32x32x16_bf16(a3, b1, acc[3][1], 0, 0, 0);
    __builtin_amdgcn_s_setprio(0);
  }
}

__global__ __launch_bounds__(512, 2) void rbf_gemm_kernel(
    const bf16x8* __restrict__ Xb, const bf16x8* __restrict__ SVb,
    const float* __restrict__ x2, const float* __restrict__ sv2,
    const float* __restrict__ DC, const float* __restrict__ gamma_p,
    float* __restrict__ out) {
  __shared__ bf16x8 As[4096];  // 4 bufs x 256 rows x 4 granules = 64 KB
  __shared__ bf16x8 Bs[4096];  // 64 KB

  const int t = threadIdx.x;
  const int lane = t & 63;
  const int wave = t >> 6;
  const int l31 = lane & 31;
  const int lhi = lane >> 5;
  const int wave_n = wave & 1;   // 0..1 -> 128 n-rows each
  const int wave_m = wave >> 1;  // 0..3 -> 64 m-cols each
  const int n0 = blockIdx.x * 256;
  const int m0 = blockIdx.y * 256;

  // fragment-read bases (granule units, 16B each); swizzle term is
  // (row>>1)&3 == (l31>>1)&3 because all row bases are multiples of 32.
  const int rsw = (l31 >> 1) & 3;
  const int aoff = (wave_n * 128 + l31) * 4;
  const int boff = (wave_m * 64 + l31) * 4;

  // staging source (pre-swizzled global address, m173 pattern):
  // thread -> LDS slot (row0 = t>>2, gs = t&3) and (row0+128, gs);
  // both use the same swizzled granule (128 rows == 0 mod 8).
  const int row0 = t >> 2;
  const int gsw = (t & 3) ^ ((row0 >> 1) & 3);
  const bf16x8* srcA = Xb + (size_t)(n0 + row0) * 64 + gsw;
  const bf16x8* srcB = SVb + (size_t)(m0 + row0) * 64 + gsw;

  f32x16 acc[4][2];
#pragma unroll
  for (int i = 0; i < 4; ++i)
#pragma unroll
    for (int j = 0; j < 2; ++j)
#pragma unroll
      for (int r = 0; r < 16; ++r) acc[i][j][r] = 0.0f;

  // prologue: fill 3 ring slots, full drain once.
  stage_tile(srcA, srcB, As, Bs, t, 0);
  stage_tile(srcA, srcB, As + 1024, Bs + 1024, t, 1);
  stage_tile(srcA, srcB, As + 2048, Bs + 2048, t, 2);
  __syncthreads();

#pragma unroll 4
  for (int kt = 0; kt < 12; ++kt) {
    const int bn = (kt + 3) & 3;
    stage_tile(srcA, srcB, As + bn * 1024, Bs + bn * 1024, t, kt + 3);
    const int bc = kt & 3;
    compute_tile(acc, As + bc * 1024, Bs + bc * 1024, aoff, boff, lhi, rsw);
    asm volatile("s_waitcnt vmcnt(8)" ::: "memory");
    __builtin_amdgcn_s_barrier();
  }
  // kt=12: last stage (tile 15 -> buf 3), then drain the tail with counted waits.
  stage_tile(srcA, srcB, As + 3072, Bs + 3072, t, 15);
  compute_tile(acc, As, Bs, aoff, boff, lhi, rsw);  // tile 12 (buf 0)
  asm volatile("s_waitcnt vmcnt(8)" ::: "memory");
  __builtin_amdgcn_s_barrier();
  compute_tile(acc, As + 1024, Bs + 1024, aoff, boff, lhi, rsw);  // tile 13
  asm volatile("s_waitcnt vmcnt(4)" ::: "memory");
  __builtin_amdgcn_s_barrier();
  compute_tile(acc, As + 2048, Bs + 2048, aoff, boff, lhi, rsw);  // tile 14
  asm volatile("s_waitcnt vmcnt(0)" ::: "memory");
  __builtin_amdgcn_s_barrier();
  compute_tile(acc, As + 3072, Bs + 3072, aoff, boff, lhi, rsw);  // tile 15

  // ---- epilogue (no barriers; identical math to verified R8 epilogue) ----
  const float g = gamma_p[0];
  const float c2 = g * 1.4426950408889634f;  // gamma * log2(e)

  float sv2v[2], dcv[2];
  const int colb = m0 + wave_m * 64 + l31;
  sv2v[0] = sv2[colb];
  dcv[0] = DC[colb];
  sv2v[1] = sv2[colb + 32];
  dcv[1] = DC[colb + 32];

#pragma unroll
  for (int i = 0; i < 4; ++i) {
    // C row = rowb + 8*g4 + r2, where reg = g4*4 + r2
    const int rowb = n0 + wave_n * 128 + i * 32 + 4 * lhi;
    float val[16];
#pragma unroll
    for (int g4 = 0; g4 < 4; ++g4) {
      f32x4 xv = *(const f32x4*)(x2 + rowb + 8 * g4);
#pragma unroll
      for (int r2 = 0; r2 < 4; ++r2) {
        const int reg = g4 * 4 + r2;
        float v = 0.0f;
#pragma unroll
        for (int j = 0; j < 2; ++j) {
          float d2 = xv[r2] + sv2v[j] - 2.0f * acc[i][j][reg];
          d2 = fmaxf(d2, 0.0f);
          v += exp2f(-c2 * d2) * dcv[j];
        }
        val[reg] = v;
      }
    }
    // reduce over 32 column-lanes: 4 DPP row-rotations (VALU pipe) + one
    // ds_swizzle xor16 (R7/R8-verified).
#pragma unroll
    for (int reg = 0; reg < 16; ++reg) {
      float v = val[reg];
      v = dpp_radd<0x121>(v);  // row_ror:1
      v = dpp_radd<0x122>(v);  // row_ror:2
      v = dpp_radd<0x124>(v);  // row_ror:4
      v = dpp_radd<0x128>(v);  // row_ror:8
      val[reg] = swz_add_xor16(v);
    }
    if (l31 == 0) {
#pragma unroll
      for (int g4 = 0; g4 < 4; ++g4)
#pragma unroll
        for (int r2 = 0; r2 < 4; ++r2)
          atomicAdd(&out[rowb + 8 * g4 + r2], val[g4 * 4 + r2]);
    }
  }
}

extern "C" void kernel_launch(void* const* d_in, const int* in_sizes, int n_in,
                              void* d_out, int out_size, void* d_ws, size_t ws_size,
                              hipStream_t stream) {
  const float* X = (const float*)d_in[0];
  const float* SV = (const float*)d_in[1];
  const float* DC = (const float*)d_in[2];
  const float* IC = (const float*)d_in[3];
  const float* gamma = (const float*)d_in[4];
  float* out = (float*)d_out;

  char* ws = (char*)d_ws;
  __bf16* Xb = (__bf16*)ws;                                   // 4 MB
  __bf16* SVb = (__bf16*)(ws + (size_t)NN * DD * 2);          // 8 MB
  float* x2 = (float*)(ws + (size_t)(NN + MM) * DD * 2);      // 16 KB
  float* sv2 = x2 + NN;                                       // 32 KB

  convert_norm_kernel<<<(NN + MM) / 4, 256, 0, stream>>>(X, SV, Xb, SVb, x2, sv2, out, IC);
  dim3 grid(NN / 256, MM / 256);
  rbf_gemm_kernel<<<grid, 512, 0, stream>>>((const bf16x8*)Xb, (const bf16x8*)SVb,
                                            x2, sv2, DC, gamma, out);
}